// Round 1
// baseline (771.289 us; speedup 1.0000x reference)
//
#include <hip/hip_runtime.h>
#include <hip/hip_bf16.h>

#define N_NODES 50000
#define N_EDGES 600000
#define D 128

// ---------------------------------------------------------------------------
// CSR build kernels
// ---------------------------------------------------------------------------
__global__ void hist_kernel(const int* __restrict__ dst, int* __restrict__ deg, int n) {
    int i = blockIdx.x * blockDim.x + threadIdx.x;
    if (i < n) atomicAdd(&deg[dst[i]], 1);
}

#define SCAN_BLOCK 1024
__global__ void scan_csr_kernel(const int* __restrict__ deg, int* __restrict__ row_start,
                                int* __restrict__ cursor, float* __restrict__ deg_inv, int n) {
    __shared__ int sh[SCAN_BLOCK];
    __shared__ int carry_s;
    int t = threadIdx.x;
    if (t == 0) carry_s = 0;
    __syncthreads();
    for (int base = 0; base < n; base += SCAN_BLOCK) {
        int i = base + t;
        int x = (i < n) ? deg[i] : 0;
        sh[t] = x;
        __syncthreads();
        int val = x;
        for (int off = 1; off < SCAN_BLOCK; off <<= 1) {
            int add = (t >= off) ? sh[t - off] : 0;
            __syncthreads();
            val += add;
            sh[t] = val;
            __syncthreads();
        }
        int incl = val;             // inclusive scan of this chunk
        int carry = carry_s;
        if (i < n) {
            int rs = carry + incl - x;   // exclusive prefix
            row_start[i] = rs;
            cursor[i] = rs;
            deg_inv[i] = 1.0f / fmaxf((float)x, 1.0f);
        }
        __syncthreads();
        if (t == SCAN_BLOCK - 1) carry_s = carry + incl;
        __syncthreads();
    }
    if (t == 0) row_start[n] = carry_s;
}

__global__ void fill_kernel(const int* __restrict__ src, const int* __restrict__ dst,
                            int* __restrict__ cursor, int* __restrict__ esrc, int n) {
    int i = blockIdx.x * blockDim.x + threadIdx.x;
    if (i < n) {
        int p = atomicAdd(&cursor[dst[i]], 1);
        esrc[p] = src[i];
    }
}

// ---------------------------------------------------------------------------
// Aggregation: msum[i] = deg_inv[i] * sum_{e in in(i)} h[src[e]]
// 2 nodes per 256-thread block; 128 threads (one column each) per node.
// ---------------------------------------------------------------------------
__global__ void agg_kernel(const float* __restrict__ h, const int* __restrict__ row_start,
                           const int* __restrict__ esrc, const float* __restrict__ deg_inv,
                           float* __restrict__ msum) {
    int node = blockIdx.x * 2 + (threadIdx.x >> 7);
    int c = threadIdx.x & 127;
    if (node >= N_NODES) return;
    int s = row_start[node];
    int e = row_start[node + 1];
    float acc = 0.f;
    for (int k = s; k < e; ++k) {
        int sn = esrc[k];
        acc += h[(size_t)sn * D + c];
    }
    msum[(size_t)node * D + c] = acc * deg_inv[node];
}

// ---------------------------------------------------------------------------
// Fused GEMM: out = relu?( h @ Ws + msum @ Wn + b )
// M-tile = 64 rows, 512 threads, each thread computes 4 rows x 4 cols.
// Two phases over the stacked K: (h, Ws) then (msum, Wn).
// LDS: in_s 32KB + W_s 64KB = 96KB -> 1 block/CU, 8 waves.
// ---------------------------------------------------------------------------
#define MT 64
__global__ __launch_bounds__(512) void gemm_kernel(
        const float* __restrict__ h, const float* __restrict__ msum,
        const float* __restrict__ Ws, const float* __restrict__ Wn,
        const float* __restrict__ bias, float* __restrict__ out, int do_relu) {
    __shared__ float in_s[MT][D];
    __shared__ float W_s[D][D];
    int tid = threadIdx.x;
    int row0 = blockIdx.x * MT;
    int cg = tid & 31;          // 32 col-groups
    int rg = tid >> 5;          // 16 row-groups
    int c0 = cg * 4;
    int r0 = rg * 4;
    float acc[4][4] = {};

    for (int phase = 0; phase < 2; ++phase) {
        const float* src = phase ? msum : h;
        const float* W   = phase ? Wn : Ws;
        if (phase) __syncthreads();   // finish compute before overwriting tiles
        // stage 64x128 input tile (2048 float4, 4 per thread)
        #pragma unroll
        for (int i = 0; i < 4; ++i) {
            int p = tid + i * 512;
            int r = p >> 5;
            int c4 = (p & 31) * 4;
            int gr = row0 + r;
            if (gr >= N_NODES) gr = N_NODES - 1;
            float4 v = *(const float4*)&src[(size_t)gr * D + c4];
            *(float4*)&in_s[r][c4] = v;
        }
        // stage 128x128 W (4096 float4, 8 per thread)
        #pragma unroll
        for (int i = 0; i < 8; ++i) {
            int p = tid + i * 512;
            int k = p >> 5;
            int c4 = (p & 31) * 4;
            float4 v = *(const float4*)&W[k * D + c4];
            *(float4*)&W_s[k][c4] = v;
        }
        __syncthreads();

        for (int k = 0; k < D; k += 4) {
            float a[4][4], bb[4][4];
            #pragma unroll
            for (int i = 0; i < 4; ++i)
                *(float4*)a[i] = *(const float4*)&in_s[r0 + i][k];
            #pragma unroll
            for (int j = 0; j < 4; ++j)
                *(float4*)bb[j] = *(const float4*)&W_s[k + j][c0];
            #pragma unroll
            for (int i = 0; i < 4; ++i)
                #pragma unroll
                for (int kk = 0; kk < 4; ++kk)
                    #pragma unroll
                    for (int j = 0; j < 4; ++j)
                        acc[i][j] += a[i][kk] * bb[kk][j];
        }
    }

    float4 bv = *(const float4*)&bias[c0];
    float bvf[4] = {bv.x, bv.y, bv.z, bv.w};
    #pragma unroll
    for (int i = 0; i < 4; ++i) {
        int gr = row0 + r0 + i;
        if (gr < N_NODES) {
            float o[4];
            #pragma unroll
            for (int j = 0; j < 4; ++j) {
                float v = acc[i][j] + bvf[j];
                o[j] = do_relu ? fmaxf(v, 0.f) : v;
            }
            *(float4*)&out[(size_t)gr * D + c0] = *(float4*)o;
        }
    }
}

// ---------------------------------------------------------------------------
// Launch
// ---------------------------------------------------------------------------
static inline size_t align_up(size_t x, size_t a) { return (x + a - 1) & ~(a - 1); }

extern "C" void kernel_launch(void* const* d_in, const int* in_sizes, int n_in,
                              void* d_out, int out_size, void* d_ws, size_t ws_size,
                              hipStream_t stream) {
    const float* g_feat = (const float*)d_in[0];
    const int* src = (const int*)d_in[1];
    const int* dst = (const int*)d_in[2];
    const float* Ws1 = (const float*)d_in[3];
    const float* Wn1 = (const float*)d_in[4];
    const float* b1  = (const float*)d_in[5];
    const float* Ws2 = (const float*)d_in[6];
    const float* Wn2 = (const float*)d_in[7];
    const float* b2  = (const float*)d_in[8];
    const float* Ws3 = (const float*)d_in[9];
    const float* Wn3 = (const float*)d_in[10];
    const float* b3  = (const float*)d_in[11];
    float* out = (float*)d_out;

    char* ws = (char*)d_ws;
    int* deg       = (int*)ws;                 ws += align_up(N_NODES * 4, 256);
    int* row_start = (int*)ws;                 ws += align_up((N_NODES + 1) * 4, 256);
    int* cursor    = (int*)ws;                 ws += align_up(N_NODES * 4, 256);
    float* deg_inv = (float*)ws;               ws += align_up(N_NODES * 4, 256);
    int* esrc      = (int*)ws;                 ws += align_up(N_EDGES * 4, 256);
    float* bufA    = (float*)ws;               ws += align_up((size_t)N_NODES * D * 4, 256);
    float* bufB    = (float*)ws;               ws += align_up((size_t)N_NODES * D * 4, 256);
    float* bufM    = (float*)ws;               ws += align_up((size_t)N_NODES * D * 4, 256);

    // ---- CSR build ----
    hipMemsetAsync(deg, 0, N_NODES * 4, stream);
    hist_kernel<<<(N_EDGES + 255) / 256, 256, 0, stream>>>(dst, deg, N_EDGES);
    scan_csr_kernel<<<1, SCAN_BLOCK, 0, stream>>>(deg, row_start, cursor, deg_inv, N_NODES);
    fill_kernel<<<(N_EDGES + 255) / 256, 256, 0, stream>>>(src, dst, cursor, esrc, N_EDGES);

    dim3 agg_grid((N_NODES + 1) / 2);
    dim3 gemm_grid((N_NODES + MT - 1) / MT);

    // ---- layer 1 ----
    agg_kernel<<<agg_grid, 256, 0, stream>>>(g_feat, row_start, esrc, deg_inv, bufM);
    gemm_kernel<<<gemm_grid, 512, 0, stream>>>(g_feat, bufM, Ws1, Wn1, b1, bufA, 1);
    // ---- layer 2 ----
    agg_kernel<<<agg_grid, 256, 0, stream>>>(bufA, row_start, esrc, deg_inv, bufM);
    gemm_kernel<<<gemm_grid, 512, 0, stream>>>(bufA, bufM, Ws2, Wn2, b2, bufB, 1);
    // ---- layer 3 ----
    agg_kernel<<<agg_grid, 256, 0, stream>>>(bufB, row_start, esrc, deg_inv, bufM);
    gemm_kernel<<<gemm_grid, 512, 0, stream>>>(bufB, bufM, Ws3, Wn3, b3, out, 0);
}

// Round 2
// 292.162 us; speedup vs baseline: 2.6399x; 2.6399x over previous
//
#include <hip/hip_runtime.h>
#include <hip/hip_bf16.h>

#define N_NODES 50000
#define N_EDGES 600000
#define D 128

typedef __bf16 bf16x8 __attribute__((ext_vector_type(8)));
typedef float f32x4 __attribute__((ext_vector_type(4)));

__device__ __forceinline__ float bits2f(unsigned int u) {
    union { unsigned int i; float f; } t; t.i = u; return t.f;
}
__device__ __forceinline__ unsigned short f2bf(float x) {
    unsigned int u = __builtin_bit_cast(unsigned int, x);
    unsigned int r = (u + 0x7fff + ((u >> 16) & 1)) >> 16;
    return (unsigned short)r;
}

// ---------------------------------------------------------------------------
// CSR build
// ---------------------------------------------------------------------------
__global__ void hist_kernel(const int* __restrict__ dst, int* __restrict__ deg, int n) {
    int i = blockIdx.x * blockDim.x + threadIdx.x;
    if (i < n) atomicAdd(&deg[dst[i]], 1);
}

__global__ void scan1_kernel(const int* __restrict__ deg, int* __restrict__ partial,
                             int* __restrict__ blk_sums) {
    __shared__ int ws[16];
    int i = blockIdx.x * 1024 + threadIdx.x;
    int x = (i < N_NODES) ? deg[i] : 0;
    int lane = threadIdx.x & 63, wid = threadIdx.x >> 6;
    int v = x;
    #pragma unroll
    for (int off = 1; off < 64; off <<= 1) {
        int t = __shfl_up(v, off);
        if (lane >= off) v += t;
    }
    if (lane == 63) ws[wid] = v;
    __syncthreads();
    if (threadIdx.x == 0) {
        int c = 0;
        #pragma unroll
        for (int j = 0; j < 16; ++j) { int t = ws[j]; ws[j] = c; c += t; }
        blk_sums[blockIdx.x] = c;
    }
    __syncthreads();
    if (i < N_NODES) partial[i] = v - x + ws[wid];
}

__global__ void scan2_kernel(int* __restrict__ blk_sums, int nb) {
    int lane = threadIdx.x;
    int v = (lane < nb) ? blk_sums[lane] : 0;
    int x = v;
    #pragma unroll
    for (int off = 1; off < 64; off <<= 1) {
        int t = __shfl_up(v, off);
        if (lane >= off) v += t;
    }
    if (lane < nb) blk_sums[lane] = v - x;
}

__global__ void scan3_kernel(const int* __restrict__ partial, const int* __restrict__ blk_sums,
                             const int* __restrict__ deg, int* __restrict__ row_start,
                             int* __restrict__ cursor, float* __restrict__ deg_inv) {
    int i = blockIdx.x * 256 + threadIdx.x;
    if (i < N_NODES) {
        int rs = partial[i] + blk_sums[i >> 10];
        row_start[i] = rs;
        cursor[i] = rs;
        deg_inv[i] = 1.0f / fmaxf((float)deg[i], 1.0f);
    }
    if (i == 0) row_start[N_NODES] = N_EDGES;
}

__global__ void fill_kernel(const int* __restrict__ src, const int* __restrict__ dst,
                            int* __restrict__ cursor, int* __restrict__ esrc, int n) {
    int i = blockIdx.x * blockDim.x + threadIdx.x;
    if (i < n) {
        int p = atomicAdd(&cursor[dst[i]], 1);
        esrc[p] = src[i];
    }
}

// ---------------------------------------------------------------------------
// f32 -> bf16 conversions
// ---------------------------------------------------------------------------
__global__ void cvt_feat_kernel(const float* __restrict__ in, unsigned short* __restrict__ out, int n4) {
    int i = blockIdx.x * blockDim.x + threadIdx.x;
    if (i < n4) {
        float4 v = *(const float4*)(in + (size_t)i * 4);
        ushort4 o;
        o.x = f2bf(v.x); o.y = f2bf(v.y); o.z = f2bf(v.z); o.w = f2bf(v.w);
        *(ushort4*)(out + (size_t)i * 4) = o;
    }
}

// transpose+convert the 6 weight matrices: WT[m][n][k] = bf16(W_m[k][n])
__global__ void cvt_w_kernel(const float* w0, const float* w1, const float* w2,
                             const float* w3, const float* w4, const float* w5,
                             unsigned short* __restrict__ o) {
    int m = blockIdx.x >> 6;
    int j = (blockIdx.x & 63) * 256 + threadIdx.x;   // 0..16383
    const float* src = m == 0 ? w0 : m == 1 ? w1 : m == 2 ? w2 : m == 3 ? w3 : m == 4 ? w4 : w5;
    int n = j >> 7, k = j & 127;
    o[m * 16384 + n * 128 + k] = f2bf(src[k * 128 + n]);
}

// ---------------------------------------------------------------------------
// Aggregation: msum[i] = bf16( deg_inv[i] * sum h[esrc] )
// 16 lanes per node, each lane owns 8 bf16 cols (uint4). Edge loop unroll x4.
// ---------------------------------------------------------------------------
__device__ __forceinline__ void acc_add(float* a, uint4 v) {
    unsigned int w[4] = {v.x, v.y, v.z, v.w};
    #pragma unroll
    for (int j = 0; j < 4; ++j) {
        a[2*j]   += bits2f(w[j] << 16);
        a[2*j+1] += bits2f(w[j] & 0xffff0000u);
    }
}

#define AGG_TPB 256
__global__ __launch_bounds__(AGG_TPB) void agg_kernel(
        const unsigned short* __restrict__ h, const int* __restrict__ row_start,
        const int* __restrict__ esrc, const float* __restrict__ deg_inv,
        unsigned short* __restrict__ msum) {
    int node = blockIdx.x * (AGG_TPB / 16) + (threadIdx.x >> 4);
    if (node >= N_NODES) return;
    int l = threadIdx.x & 15;
    int s = row_start[node], e = row_start[node + 1];
    const unsigned short* hl = h + l * 8;
    float acc[8] = {0, 0, 0, 0, 0, 0, 0, 0};
    int k = s;
    for (; k + 4 <= e; k += 4) {
        int i0 = esrc[k], i1 = esrc[k + 1], i2 = esrc[k + 2], i3 = esrc[k + 3];
        uint4 v0 = *(const uint4*)(hl + (size_t)i0 * D);
        uint4 v1 = *(const uint4*)(hl + (size_t)i1 * D);
        uint4 v2 = *(const uint4*)(hl + (size_t)i2 * D);
        uint4 v3 = *(const uint4*)(hl + (size_t)i3 * D);
        acc_add(acc, v0); acc_add(acc, v1); acc_add(acc, v2); acc_add(acc, v3);
    }
    for (; k < e; ++k) {
        uint4 v = *(const uint4*)(hl + (size_t)esrc[k] * D);
        acc_add(acc, v);
    }
    float di = deg_inv[node];
    unsigned short o[8];
    #pragma unroll
    for (int j = 0; j < 8; ++j) o[j] = f2bf(acc[j] * di);
    *(uint4*)(msum + (size_t)node * D + l * 8) = *(uint4*)o;
}

// ---------------------------------------------------------------------------
// MFMA GEMM: out = relu?( h @ Ws + msum @ Wn + b )
// BM=64, BN=128, K=128 x 2 phases. 256 threads (4 waves), wave w owns cols
// [32w, 32w+32). LDS: As 16KB + Bs(transposed W) 32KB = 48KB, XOR-swizzled.
// ---------------------------------------------------------------------------
__global__ __launch_bounds__(256) void gemm_kernel(
        const unsigned short* __restrict__ h, const unsigned short* __restrict__ msum,
        const unsigned short* __restrict__ WsT, const unsigned short* __restrict__ WnT,
        const float* __restrict__ bias, void* __restrict__ outp,
        int do_relu, int store_f32) {
    __shared__ char lds[49152];
    char* As = lds;              // [64][128] bf16, row stride 256B, swizzled
    char* Bs = lds + 16384;      // [128][128] bf16 (W transposed: [n][k]), swizzled
    int tid = threadIdx.x;
    int l = tid & 63;
    int w = tid >> 6;
    int row0 = blockIdx.x * 64;

    f32x4 acc[4][2];
    #pragma unroll
    for (int mt = 0; mt < 4; ++mt)
        #pragma unroll
        for (int nt = 0; nt < 2; ++nt)
            acc[mt][nt] = (f32x4)0.0f;

    for (int phase = 0; phase < 2; ++phase) {
        const unsigned short* A = phase ? msum : h;
        const unsigned short* B = phase ? WnT : WsT;
        if (phase) __syncthreads();
        #pragma unroll
        for (int i = 0; i < 4; ++i) {               // stage A: 1024 x 16B
            int c = tid + i * 256;
            int r = c >> 4, kb = (c & 15) << 4;
            int gr = row0 + r; if (gr >= N_NODES) gr = N_NODES - 1;
            uint4 v = *(const uint4*)(A + (size_t)gr * D + ((c & 15) << 3));
            *(uint4*)(As + r * 256 + (kb ^ ((r & 7) << 4))) = v;
        }
        #pragma unroll
        for (int i = 0; i < 8; ++i) {               // stage B: 2048 x 16B
            int c = tid + i * 256;
            int r = c >> 4, kb = (c & 15) << 4;
            uint4 v = *(const uint4*)(B + (size_t)r * D + ((c & 15) << 3));
            *(uint4*)(Bs + r * 256 + (kb ^ ((r & 7) << 4))) = v;
        }
        __syncthreads();

        #pragma unroll
        for (int ks = 0; ks < 4; ++ks) {
            int kb = ks * 64 + ((l >> 4) << 4);
            bf16x8 a[4], b[2];
            #pragma unroll
            for (int mt = 0; mt < 4; ++mt) {
                int r = mt * 16 + (l & 15);
                a[mt] = *(const bf16x8*)(As + r * 256 + (kb ^ ((r & 7) << 4)));
            }
            #pragma unroll
            for (int nt = 0; nt < 2; ++nt) {
                int r = w * 32 + nt * 16 + (l & 15);
                b[nt] = *(const bf16x8*)(Bs + r * 256 + (kb ^ ((r & 7) << 4)));
            }
            #pragma unroll
            for (int mt = 0; mt < 4; ++mt)
                #pragma unroll
                for (int nt = 0; nt < 2; ++nt)
                    acc[mt][nt] = __builtin_amdgcn_mfma_f32_16x16x32_bf16(a[mt], b[nt], acc[mt][nt], 0, 0, 0);
        }
    }

    #pragma unroll
    for (int nt = 0; nt < 2; ++nt) {
        int col = w * 32 + nt * 16 + (l & 15);
        float bv = bias[col];
        #pragma unroll
        for (int mt = 0; mt < 4; ++mt) {
            #pragma unroll
            for (int r = 0; r < 4; ++r) {
                int grow = row0 + mt * 16 + ((l >> 4) << 2) + r;
                if (grow < N_NODES) {
                    float v = acc[mt][nt][r] + bv;
                    if (do_relu) v = fmaxf(v, 0.f);
                    if (store_f32) ((float*)outp)[(size_t)grow * D + col] = v;
                    else ((unsigned short*)outp)[(size_t)grow * D + col] = f2bf(v);
                }
            }
        }
    }
}

// ---------------------------------------------------------------------------
// Launch
// ---------------------------------------------------------------------------
static inline size_t align_up(size_t x, size_t a) { return (x + a - 1) & ~(a - 1); }

extern "C" void kernel_launch(void* const* d_in, const int* in_sizes, int n_in,
                              void* d_out, int out_size, void* d_ws, size_t ws_size,
                              hipStream_t stream) {
    const float* g_feat = (const float*)d_in[0];
    const int* src = (const int*)d_in[1];
    const int* dst = (const int*)d_in[2];
    const float* Ws1 = (const float*)d_in[3];
    const float* Wn1 = (const float*)d_in[4];
    const float* b1  = (const float*)d_in[5];
    const float* Ws2 = (const float*)d_in[6];
    const float* Wn2 = (const float*)d_in[7];
    const float* b2  = (const float*)d_in[8];
    const float* Ws3 = (const float*)d_in[9];
    const float* Wn3 = (const float*)d_in[10];
    const float* b3  = (const float*)d_in[11];
    float* out = (float*)d_out;

    char* ws = (char*)d_ws;
    int* deg        = (int*)ws;            ws += align_up(N_NODES * 4, 256);
    int* row_start  = (int*)ws;            ws += align_up((N_NODES + 1) * 4, 256);
    int* cursor     = (int*)ws;            ws += align_up(N_NODES * 4, 256);
    float* deg_inv  = (float*)ws;          ws += align_up(N_NODES * 4, 256);
    int* partial    = (int*)ws;            ws += align_up(N_NODES * 4, 256);
    int* blk_sums   = (int*)ws;            ws += align_up(64 * 4, 256);
    int* esrc       = (int*)ws;            ws += align_up(N_EDGES * 4, 256);
    unsigned short* g_bf = (unsigned short*)ws;  ws += align_up((size_t)N_NODES * D * 2, 256);
    unsigned short* WT   = (unsigned short*)ws;  ws += align_up(6 * 128 * 128 * 2, 256);
    unsigned short* bufA = (unsigned short*)ws;  ws += align_up((size_t)N_NODES * D * 2, 256);
    unsigned short* bufB = (unsigned short*)ws;  ws += align_up((size_t)N_NODES * D * 2, 256);
    unsigned short* bufM = (unsigned short*)ws;  ws += align_up((size_t)N_NODES * D * 2, 256);

    // CSR build + conversions
    hipMemsetAsync(deg, 0, N_NODES * 4, stream);
    hist_kernel<<<(N_EDGES + 255) / 256, 256, 0, stream>>>(dst, deg, N_EDGES);
    cvt_feat_kernel<<<((N_NODES * D / 4) + 255) / 256, 256, 0, stream>>>(g_feat, g_bf, N_NODES * D / 4);
    cvt_w_kernel<<<6 * 64, 256, 0, stream>>>(Ws1, Wn1, Ws2, Wn2, Ws3, Wn3, WT);
    int nb = (N_NODES + 1023) / 1024;
    scan1_kernel<<<nb, 1024, 0, stream>>>(deg, partial, blk_sums);
    scan2_kernel<<<1, 64, 0, stream>>>(blk_sums, nb);
    scan3_kernel<<<(N_NODES + 255) / 256, 256, 0, stream>>>(partial, blk_sums, deg, row_start, cursor, deg_inv);
    fill_kernel<<<(N_EDGES + 255) / 256, 256, 0, stream>>>(src, dst, cursor, esrc, N_EDGES);

    dim3 agg_grid((N_NODES * 16 + AGG_TPB - 1) / AGG_TPB);
    dim3 gemm_grid((N_NODES + 63) / 64);
    const unsigned short *WsT1 = WT, *WnT1 = WT + 16384, *WsT2 = WT + 2*16384,
                         *WnT2 = WT + 3*16384, *WsT3 = WT + 4*16384, *WnT3 = WT + 5*16384;

    // layer 1
    agg_kernel<<<agg_grid, AGG_TPB, 0, stream>>>(g_bf, row_start, esrc, deg_inv, bufM);
    gemm_kernel<<<gemm_grid, 256, 0, stream>>>(g_bf, bufM, WsT1, WnT1, b1, bufA, 1, 0);
    // layer 2
    agg_kernel<<<agg_grid, AGG_TPB, 0, stream>>>(bufA, row_start, esrc, deg_inv, bufM);
    gemm_kernel<<<gemm_grid, 256, 0, stream>>>(bufA, bufM, WsT2, WnT2, b2, bufB, 1, 0);
    // layer 3
    agg_kernel<<<agg_grid, AGG_TPB, 0, stream>>>(bufB, row_start, esrc, deg_inv, bufM);
    gemm_kernel<<<gemm_grid, 256, 0, stream>>>(bufB, bufM, WsT3, WnT3, b3, out, 0, 1);
}